// Round 1
// baseline (10042.783 us; speedup 1.0000x reference)
//
#include <hip/hip_runtime.h>
#include <hip/hip_bf16.h>

#define NPTS 16384
#define MCENT 4096
#define BCLD 2
#define FDIM 32
#define H1DIM 64
#define CODIM 128
#define KNBR 64
// largest fp32 <= 0.04 (float64) == fp32(0.04f) == 0.039999999105930328
#define R2CUT 0.04f

// Exact (numpy-order, contraction-free) squared distance: ((dx*dx+dy*dy)+dz*dz)
__device__ __forceinline__ float d2e(float ax, float ay, float az,
                                     float bx, float by, float bz) {
  float dx = __fsub_rn(ax, bx);
  float dy = __fsub_rn(ay, by);
  float dz = __fsub_rn(az, bz);
  return __fadd_rn(__fadd_rn(__fmul_rn(dx, dx), __fmul_rn(dy, dy)), __fmul_rn(dz, dz));
}

// ---------------- Kernel 1: farthest point sampling (1 block per cloud) ----
__global__ __launch_bounds__(1024) void fps_kernel(const float* __restrict__ pos,
                                                   int* __restrict__ fps_idx) {
  const int b = blockIdx.x;
  const float* P = pos + (size_t)b * NPTS * 3;
  const int t = threadIdx.x;

  float px[16], py[16], pz[16], d[16];
#pragma unroll
  for (int j = 0; j < 16; ++j) {
    int g = t * 16 + j;
    px[j] = P[3 * g + 0];
    py[j] = P[3 * g + 1];
    pz[j] = P[3 * g + 2];
  }
  const float x0 = P[0], y0 = P[1], z0 = P[2];
#pragma unroll
  for (int j = 0; j < 16; ++j) d[j] = d2e(px[j], py[j], pz[j], x0, y0, z0);

  if (t == 0) fps_idx[b * MCENT] = 0;

  __shared__ unsigned long long wkey[16];
  __shared__ float win[3];

  for (int m = 1; m < MCENT; ++m) {
    // local argmax over 16 (strictly-greater keeps lowest j => lowest global idx)
    float best = d[0];
    int bj = 0;
#pragma unroll
    for (int j = 1; j < 16; ++j) {
      if (d[j] > best) { best = d[j]; bj = j; }
    }
    // pack: hi = d bits (d>=0 so uint order == float order), lo = ~gidx (tie -> lower idx)
    unsigned long long key = ((unsigned long long)__float_as_uint(best) << 32)
                           | (unsigned long long)(unsigned)(~(unsigned)(t * 16 + bj));
#pragma unroll
    for (int off = 32; off >= 1; off >>= 1) {
      unsigned long long o = __shfl_xor(key, off);
      if (o > key) key = o;
    }
    if ((t & 63) == 0) wkey[t >> 6] = key;
    __syncthreads();  // barrier A: wkey published; prior win reads all done

    unsigned long long kk = wkey[0];
#pragma unroll
    for (int w = 1; w < 16; ++w) {
      unsigned long long o = wkey[w];
      if (o > kk) kk = o;
    }
    const unsigned g = ~(unsigned)kk;  // winner global (local-to-cloud) index

    if (t == (int)(g >> 4)) {
      float sx = px[0], sy = py[0], sz = pz[0];
#pragma unroll
      for (int j = 1; j < 16; ++j) {
        if ((int)(g & 15u) == j) { sx = px[j]; sy = py[j]; sz = pz[j]; }
      }
      win[0] = sx; win[1] = sy; win[2] = sz;
    }
    if (t == 0) fps_idx[b * MCENT + m] = (int)g;
    __syncthreads();  // barrier B: win published

    const float wx = win[0], wy = win[1], wz = win[2];
#pragma unroll
    for (int j = 0; j < 16; ++j)
      d[j] = fminf(d[j], d2e(px[j], py[j], pz[j], wx, wy, wz));
  }
}

// ------------- Kernel 2: ball query + K-smallest selection (1 wave/centroid) --
__global__ __launch_bounds__(256) void ballq_kernel(const float* __restrict__ pos,
                                                    const int* __restrict__ fps_idx,
                                                    int* __restrict__ nbr,
                                                    float* __restrict__ out_pc,
                                                    float* __restrict__ out_batch) {
  const int wave = threadIdx.x >> 6;
  const int lane = threadIdx.x & 63;
  const int c = blockIdx.x * 4 + wave;   // global centroid id
  const int b = c >> 12;                 // 4096 centroids per cloud
  const float* P = pos + (size_t)b * NPTS * 3;

  const int ci = fps_idx[c];
  const float cx = P[3 * ci + 0];
  const float cy = P[3 * ci + 1];
  const float cz = P[3 * ci + 2];
  if (lane == 0) {
    out_pc[3 * c + 0] = cx;
    out_pc[3 * c + 1] = cy;
    out_pc[3 * c + 2] = cz;
    out_batch[c] = (float)b;
  }

  __shared__ unsigned long long list[4][1024];
  __shared__ int cnt[4];
  if (lane == 0) cnt[wave] = 0;   // same-wave program order precedes the atomics

  for (int i = lane; i < NPTS; i += 64) {
    const float qx = P[3 * i + 0];
    const float qy = P[3 * i + 1];
    const float qz = P[3 * i + 2];
    const float dd = d2e(cx, cy, cz, qx, qy, qz);
    if (dd <= R2CUT) {
      int p = atomicAdd(&cnt[wave], 1);
      if (p < 1024)
        list[wave][p] = ((unsigned long long)__float_as_uint(dd) << 32)
                      | (unsigned long long)(unsigned)i;
    }
  }
  __syncthreads();

  int n = cnt[wave];
  if (n > 1024) n = 1024;

  // per-lane candidate registers (strided), sentinel = ~0
  unsigned long long loc[16];
#pragma unroll
  for (int k = 0; k < 16; ++k) {
    int i = lane + k * 64;
    loc[k] = (i < n) ? list[wave][i] : ~0ULL;
  }
  unsigned long long mv = loc[0];
#pragma unroll
  for (int k = 1; k < 16; ++k)
    if (loc[k] < mv) mv = loc[k];

  int myout = -1;
  for (int s = 0; s < 64; ++s) {
    unsigned long long wmin = mv;
#pragma unroll
    for (int off = 32; off >= 1; off >>= 1) {
      unsigned long long o = __shfl_xor(wmin, off);
      if (o < wmin) wmin = o;
    }
    if (lane == s) myout = (wmin == ~0ULL) ? -1 : (int)(unsigned)wmin;
    if (mv == wmin && wmin != ~0ULL) {  // unique owner: keys carry the index
#pragma unroll
      for (int k = 0; k < 16; ++k)
        if (loc[k] == wmin) loc[k] = ~0ULL;
      mv = loc[0];
#pragma unroll
      for (int k = 1; k < 16; ++k)
        if (loc[k] < mv) mv = loc[k];
    }
  }
  nbr[c * KNBR + lane] = myout;
}

// ------------- Kernel 3: MLP (35->64 relu ->128) + masked max-pool ----------
__global__ __launch_bounds__(256) void mlp_kernel(const float* __restrict__ pos,
                                                  const float* __restrict__ x,
                                                  const int* __restrict__ fps_idx,
                                                  const int* __restrict__ nbr,
                                                  const float* __restrict__ W1,
                                                  const float* __restrict__ b1,
                                                  const float* __restrict__ W2,
                                                  const float* __restrict__ b2,
                                                  float* __restrict__ out) {
  const int c = blockIdx.x;
  const int b = c >> 12;
  const float* P = pos + (size_t)b * NPTS * 3;
  const float* X = x + (size_t)b * NPTS * FDIM;

  __shared__ float W1s[35 * 64];
  __shared__ float W2s[64 * 128];
  __shared__ float b1s[64];
  __shared__ float b2s[128];
  __shared__ float h1s[64][64];
  __shared__ float pmax[2][128];
  __shared__ int validk[64];

  const int tid = threadIdx.x;
  for (int i = tid; i < 35 * 64; i += 256) W1s[i] = W1[i];
  for (int i = tid; i < 64 * 128; i += 256) W2s[i] = W2[i];
  if (tid < 64) b1s[tid] = b1[tid];
  else if (tid < 192) b2s[tid - 64] = b2[tid - 64];

  const int ci = fps_idx[c];
  const float c5x = P[3 * ci + 0] / 0.2f;  // faithful: pos_i / r
  const float c5y = P[3 * ci + 1] / 0.2f;
  const float c5z = P[3 * ci + 2] / 0.2f;

  // phase 1: thread (k = tid>>2, q = tid&3) computes hidden units [q*16, q*16+16)
  const int k = tid >> 2, q = tid & 3;
  const int nk = nbr[c * KNBR + k];
  if (q == 0) validk[k] = (nk >= 0) ? 1 : 0;
  const int nkc = (nk < 0) ? 0 : nk;

  float msg[35];
  const float4* Xr = (const float4*)(X + (size_t)nkc * FDIM);
#pragma unroll
  for (int i4 = 0; i4 < 8; ++i4) {
    float4 v = Xr[i4];
    msg[i4 * 4 + 0] = v.x; msg[i4 * 4 + 1] = v.y;
    msg[i4 * 4 + 2] = v.z; msg[i4 * 4 + 3] = v.w;
  }
  msg[32] = P[3 * nkc + 0] - c5x;
  msg[33] = P[3 * nkc + 1] - c5y;
  msg[34] = P[3 * nkc + 2] - c5z;

  __syncthreads();  // W1s/W2s/b/validk ready

  float acc[16];
#pragma unroll
  for (int h = 0; h < 16; ++h) acc[h] = b1s[q * 16 + h];
#pragma unroll
  for (int i = 0; i < 35; ++i) {
    const float m = msg[i];
    const float4* wrow = (const float4*)&W1s[i * 64 + q * 16];
#pragma unroll
    for (int j4 = 0; j4 < 4; ++j4) {
      float4 w = wrow[j4];
      acc[j4 * 4 + 0] += m * w.x;
      acc[j4 * 4 + 1] += m * w.y;
      acc[j4 * 4 + 2] += m * w.z;
      acc[j4 * 4 + 3] += m * w.w;
    }
  }
#pragma unroll
  for (int h = 0; h < 16; ++h) h1s[k][q * 16 + h] = fmaxf(acc[h], 0.0f);
  __syncthreads();

  // phase 2: thread (ch = tid&127, half = tid>>7) max-pools 32 neighbors
  const int ch = tid & 127, half = tid >> 7;
  float w2r[64];
#pragma unroll
  for (int i = 0; i < 64; ++i) w2r[i] = W2s[i * 128 + ch];

  float mx = -INFINITY;
  for (int k2 = half * 32; k2 < half * 32 + 32; ++k2) {
    if (!validk[k2]) continue;
    float s = b2s[ch];
    const float4* hr = (const float4*)h1s[k2];
#pragma unroll
    for (int i4 = 0; i4 < 16; ++i4) {
      float4 h4 = hr[i4];
      s += h4.x * w2r[i4 * 4 + 0] + h4.y * w2r[i4 * 4 + 1]
         + h4.z * w2r[i4 * 4 + 2] + h4.w * w2r[i4 * 4 + 3];
    }
    mx = fmaxf(mx, s);
  }
  pmax[half][ch] = mx;
  __syncthreads();

  if (tid < 128) {
    float m2 = fmaxf(pmax[0][tid], pmax[1][tid]);
    out[(size_t)c * CODIM + tid] = (m2 > -INFINITY) ? m2 : 0.0f;
  }
}

extern "C" void kernel_launch(void* const* d_in, const int* in_sizes, int n_in,
                              void* d_out, int out_size, void* d_ws, size_t ws_size,
                              hipStream_t stream) {
  const float* x   = (const float*)d_in[0];
  const float* pos = (const float*)d_in[1];
  const float* W1  = (const float*)d_in[3];
  const float* b1  = (const float*)d_in[4];
  const float* W2  = (const float*)d_in[5];
  const float* b2  = (const float*)d_in[6];
  float* out = (float*)d_out;

  int* fps_idx = (int*)d_ws;            // B*M ints          = 32 KiB
  int* nbr     = (int*)d_ws + BCLD * MCENT;  // B*M*K ints   = 2 MiB

  float* out_pc    = out + (size_t)BCLD * MCENT * CODIM;  // offset 1048576
  float* out_batch = out_pc + (size_t)BCLD * MCENT * 3;   // offset 1073152

  hipLaunchKernelGGL(fps_kernel, dim3(BCLD), dim3(1024), 0, stream, pos, fps_idx);
  hipLaunchKernelGGL(ballq_kernel, dim3(BCLD * MCENT / 4), dim3(256), 0, stream,
                     pos, fps_idx, nbr, out_pc, out_batch);
  hipLaunchKernelGGL(mlp_kernel, dim3(BCLD * MCENT), dim3(256), 0, stream,
                     pos, x, fps_idx, nbr, W1, b1, W2, b2, out);
}